// Round 6
// baseline (223.257 us; speedup 1.0000x reference)
//
#include <hip/hip_runtime.h>
#include <math.h>

// TopKMoEGate via split-bf16 MFMA:
//   x = xh + xl, W = wh + wl (bf16 hi/lo); logits = xh*wh + xh*wl + xl*wh
//   (fp32-accurate to ~5e-6; wave-parallel fp64 tie-guard on top-3 candidates).
// R13: revert to R10's PROVEN 3-term numerics + layout (R11/R12's 1-term bf16
//     failed deterministically: sigma~2.3e-3 lets the true #2 expert sink to
//     bf16-rank>=4, outside the top-3 guard's candidate set; P ~ O(1) over
//     16384 tokens. 3-term sigma~5e-6 makes that probability ~1e-4 -> safe.)
//     Kept from R12 (safe-only): s_waitcnt lgkmcnt(0) belt + compiler fence at
//     the barrier. New: perm-packed split2 (v_perm_b32 packs two hi-bf16 in
//     one op; bit-identical truncation bytes) -> ~3 VALU ops/element vs ~9,
//     cutting the dominant VALU phase of the per-chunk convoy.
//     Pipeline: counted vmcnt(3) (never 0 in-loop), raw s_barrier, 3 buffers,
//     depth-2 prefetch, 3 DMA loads/wave/chunk (uniform vmcnt accounting).
//     TM=32 tokens, BK=64, 8 waves = 2 token-halves x 4 expert-quarters.
//     LDS 72 KB -> 2 blocks/CU; logits aliased onto staging area post-loop.

typedef __attribute__((ext_vector_type(8))) __bf16 bf16x8;
typedef __attribute__((ext_vector_type(8))) unsigned short u16x8;
typedef __attribute__((ext_vector_type(4))) float f32x4;
typedef __attribute__((ext_vector_type(4))) unsigned u32x4;

constexpr int EXPN = 64;   // experts
constexpr int TM   = 32;   // tokens per block
constexpr int BK   = 64;   // k per chunk
constexpr int WBYTES = EXPN * 2 * BK * 2;          // 16384 B W tile (hi+lo)
constexpr int XBYTES = TM * BK * 4;                // 8192 B x tile
constexpr int BUFB   = WBYTES + XBYTES;            // 24576 B per buffer

__device__ __forceinline__ void split2(float f, unsigned short& h, unsigned short& l) {
    const unsigned b = __float_as_uint(f);
    h = (unsigned short)(b >> 16);                       // bf16 hi (truncate)
    const float fh = __uint_as_float(b & 0xffff0000u);
    l = (unsigned short)(__float_as_uint(f - fh) >> 16); // bf16 lo
}

__device__ __forceinline__ bf16x8 as_bf16(u16x8 v) {
    union { u16x8 u; bf16x8 b; } c; c.u = v; return c.b;
}
__device__ __forceinline__ bf16x8 as_bf16_u32(u32x4 v) {
    union { u32x4 u; bf16x8 b; } c; c.u = v; return c.b;
}

// async global -> LDS DMA, 16 B per lane; LDS dest = wave-uniform base + lane*16
__device__ __forceinline__ void gload16(const void* g, void* l) {
    typedef __attribute__((address_space(1))) void gv;
    typedef __attribute__((address_space(3))) void lv;
    __builtin_amdgcn_global_load_lds((gv*)g, (lv*)l, 16, 0, 0);
}

// ---- pre-kernel: W fp32 -> wh/wl bf16 planes (same split2 numerics) ----
__global__ __launch_bounds__(256)
void convert_w_kernel(const float* __restrict__ W,
                      unsigned short* __restrict__ whp,
                      unsigned short* __restrict__ wlp, int n4)
{
    const int i = blockIdx.x * 256 + threadIdx.x;   // float4 index
    if (i >= n4) return;
    const float4 v = *(const float4*)(W + (size_t)i * 4);
    const float f[4] = {v.x, v.y, v.z, v.w};
    unsigned short h[4], l[4];
#pragma unroll
    for (int j = 0; j < 4; ++j) split2(f[j], h[j], l[j]);
    *(ushort4*)(whp + (size_t)i * 4) = make_ushort4(h[0], h[1], h[2], h[3]);
    *(ushort4*)(wlp + (size_t)i * 4) = make_ushort4(l[0], l[1], l[2], l[3]);
}

__global__ __launch_bounds__(512, 4)
void moe_gate_kernel(const float* __restrict__ x,      // [M, D]
                     const float* __restrict__ W,      // [E, D] (fp64 guard only)
                     const unsigned short* __restrict__ whp,  // [E, D] bf16 hi
                     const unsigned short* __restrict__ wlp,  // [E, D] bf16 lo
                     const float* __restrict__ nw,     // [E]
                     const float* __restrict__ noise,  // [M, E]
                     float* __restrict__ probs,        // [M, E]
                     float* __restrict__ idx_out,      // [M, 2] float-encoded
                     float* __restrict__ val_out,      // [M, 2]
                     int D)
{
    // buffer b: W tile at smem + b*BUFB (64 rows x 256 B: [hi 128B | lo 128B]),
    //           x tile at smem + b*BUFB + WBYTES (32 rows x 256 B fp32)
    // 16-byte granules, 16/row; stored slot s of row r holds logical granule
    // s ^ (r & 7)  (XOR touches low 3 bits only -> hi/lo plane bit preserved)
    __shared__ __align__(16) char smem[3 * BUFB];    // 72 KB

    const int tid  = threadIdx.x;
    const int lane = tid & 63;
    const int wv   = tid >> 6;          // 0..7
    const int th   = wv >> 2;           // token half
    const int eq   = wv & 3;            // expert quarter
    const int m0   = blockIdx.x * TM;

    const int fr = lane & 15;           // A row (token) / B row (expert) in frag
    const int kq = (lane >> 4) * 8;     // k sub-offset in frag (0,8,16,24)
    const int f7 = fr & 7;

    // ---- staging sources (pre-swizzled per-lane global pointers) ----
    const int sl   = lane >> 4;         // sub-row within 1 KB inst (4 rows/inst)
    const int slot = lane & 15;         // granule slot within 256 B row
    // W: 16 insts/chunk; wave wv issues insts j0 = 2wv, j1 = 2wv+1
    const int j0 = wv * 2, j1 = j0 + 1;
    const int we0 = j0 * 4 + sl, we1 = j1 * 4 + sl;      // expert rows
    const int wg0 = slot ^ (we0 & 7), wg1 = slot ^ (we1 & 7); // logical granule
    const unsigned short* wsrc0 = ((wg0 < 8) ? whp : wlp)
                                + (size_t)we0 * D + (wg0 & 7) * 8;
    const unsigned short* wsrc1 = ((wg1 < 8) ? whp : wlp)
                                + (size_t)we1 * D + (wg1 & 7) * 8;
    // x: 8 insts/chunk; wave wv issues inst wv
    const int xrow = wv * 4 + sl;
    const int xg   = (slot & 8) | ((slot & 7) ^ (xrow & 7));   // logical granule
    const float* xsrc = x + (size_t)(m0 + xrow) * D + xg * 4;

#define STAGE(b, c) {                                                     \
        char* bb_ = smem + (b) * BUFB;                                    \
        gload16(wsrc0 + (size_t)(c) * BK, bb_ + j0 * 1024);               \
        gload16(wsrc1 + (size_t)(c) * BK, bb_ + j1 * 1024);               \
        gload16(xsrc  + (size_t)(c) * BK, bb_ + WBYTES + wv * 1024);      \
    }

    f32x4 acc = {0.f, 0.f, 0.f, 0.f};

#define COMPUTE(b) {                                                              \
        const char* wbp_ = smem + (b) * BUFB;                                     \
        const char* xbp_ = wbp_ + WBYTES;                                         \
        _Pragma("unroll")                                                         \
        for (int ks_ = 0; ks_ < 2; ++ks_) {                                       \
            const int kk_ = ks_ * 32 + kq;                                        \
            const int sx_ = (kk_ >> 2) ^ f7;      /* even logical granule */      \
            const float4 xa_ = *(const float4*)(xbp_ + (th*16+fr)*256 + sx_*16);  \
            const float4 xc_ = *(const float4*)(xbp_ + (th*16+fr)*256 + (sx_^1)*16); \
            const int gh_ = kk_ >> 3;                                             \
            const u16x8 bh_ = *(const u16x8*)(wbp_ + (eq*16+fr)*256 + (gh_ ^ f7)*16); \
            const u16x8 bl_ = *(const u16x8*)(wbp_ + (eq*16+fr)*256 + (8 + (gh_ ^ f7))*16); \
            /* perm-packed split2: hi = bytes[3:2] of f (truncate); lo = bytes  */\
            /* [3:2] of (f - fh). Bit-identical to scalar split2.               */\
            const unsigned u0_=__float_as_uint(xa_.x), u1_=__float_as_uint(xa_.y),\
                           u2_=__float_as_uint(xa_.z), u3_=__float_as_uint(xa_.w),\
                           u4_=__float_as_uint(xc_.x), u5_=__float_as_uint(xc_.y),\
                           u6_=__float_as_uint(xc_.z), u7_=__float_as_uint(xc_.w);\
            u32x4 hp_, lp_;                                                       \
            hp_[0] = __builtin_amdgcn_perm(u1_, u0_, 0x07060302u);                \
            hp_[1] = __builtin_amdgcn_perm(u3_, u2_, 0x07060302u);                \
            hp_[2] = __builtin_amdgcn_perm(u5_, u4_, 0x07060302u);                \
            hp_[3] = __builtin_amdgcn_perm(u7_, u6_, 0x07060302u);                \
            const unsigned d0_=__float_as_uint(xa_.x-__uint_as_float(u0_&0xffff0000u));\
            const unsigned d1_=__float_as_uint(xa_.y-__uint_as_float(u1_&0xffff0000u));\
            const unsigned d2_=__float_as_uint(xa_.z-__uint_as_float(u2_&0xffff0000u));\
            const unsigned d3_=__float_as_uint(xa_.w-__uint_as_float(u3_&0xffff0000u));\
            const unsigned d4_=__float_as_uint(xc_.x-__uint_as_float(u4_&0xffff0000u));\
            const unsigned d5_=__float_as_uint(xc_.y-__uint_as_float(u5_&0xffff0000u));\
            const unsigned d6_=__float_as_uint(xc_.z-__uint_as_float(u6_&0xffff0000u));\
            const unsigned d7_=__float_as_uint(xc_.w-__uint_as_float(u7_&0xffff0000u));\
            lp_[0] = __builtin_amdgcn_perm(d1_, d0_, 0x07060302u);                \
            lp_[1] = __builtin_amdgcn_perm(d3_, d2_, 0x07060302u);                \
            lp_[2] = __builtin_amdgcn_perm(d5_, d4_, 0x07060302u);                \
            lp_[3] = __builtin_amdgcn_perm(d7_, d6_, 0x07060302u);                \
            const bf16x8 ah_ = as_bf16_u32(hp_), al_ = as_bf16_u32(lp_);          \
            acc = __builtin_amdgcn_mfma_f32_16x16x32_bf16(ah_, as_bf16(bh_), acc, 0, 0, 0); \
            acc = __builtin_amdgcn_mfma_f32_16x16x32_bf16(ah_, as_bf16(bl_), acc, 0, 0, 0); \
            acc = __builtin_amdgcn_mfma_f32_16x16x32_bf16(al_, as_bf16(bh_), acc, 0, 0, 0); \
        }                                                                         \
    }

    const int nchunk = D / BK;          // 32
    STAGE(0, 0)
    STAGE(1, 1)

    for (int c = 0; c < nchunk; ++c) {
        // belt: my ds_reads from the previous iteration are COMPLETE before I
        // pass the barrier -> the STAGE issued after the barrier can never
        // overwrite a pending read.
        asm volatile("s_waitcnt lgkmcnt(0)" ::: "memory");
        // counted drain: chunk c's 3 loads done, chunk c+1's 3 stay in flight
        if (c < nchunk - 1) asm volatile("s_waitcnt vmcnt(3)" ::: "memory");
        else                asm volatile("s_waitcnt vmcnt(0)" ::: "memory");
        __builtin_amdgcn_s_barrier();   // raw barrier: no vmcnt(0) drain
        asm volatile("" ::: "memory");  // fence: nothing hoists above
        if (c + 2 < nchunk) STAGE((c + 2) % 3, c + 2)
        COMPUTE(c % 3)
    }

#undef STAGE
#undef COMPUTE

    __syncthreads();   // all waves done reading buffers; safe to alias logits

    // ---- C/D layout: col = lane&15 (expert), row = (lane>>4)*4 + reg (token) ----
    float (*ls)[EXPN + 1] = (float (*)[EXPN + 1])smem;   // 32 x 65 fp32 = 8.3 KB
    const int trow = th * 16 + (lane >> 4) * 4;
#pragma unroll
    for (int r = 0; r < 4; ++r)
        ls[trow + r][eq * 16 + fr] = acc[r];
    __syncthreads();

    // ---- epilogue: per-token noisy top-2 + sparse softmax (lane = expert) ----
    const float nwv = nw[lane];

#pragma unroll 1
    for (int t = 0; t < 4; ++t) {
        const int tl = wv * 4 + t;       // local token (8 waves x 4 = 32)
        const int g  = m0 + tl;          // global token
        const float logit = fmaf(noise[(size_t)g * EXPN + lane], nwv, ls[tl][lane]);

        float v0; int i0;
        {
            float v = logit; int ix = lane;
#pragma unroll
            for (int off = 32; off; off >>= 1) {
                const float vo = __shfl_xor(v, off);
                const int   io = __shfl_xor(ix, off);
                if (vo > v || (vo == v && io < ix)) { v = vo; ix = io; }
            }
            v0 = v; i0 = ix;
        }
        float v1; int i1;
        {
            float v = (lane == i0) ? -INFINITY : logit; int ix = lane;
#pragma unroll
            for (int off = 32; off; off >>= 1) {
                const float vo = __shfl_xor(v, off);
                const int   io = __shfl_xor(ix, off);
                if (vo > v || (vo == v && io < ix)) { v = vo; ix = io; }
            }
            v1 = v; i1 = ix;
        }
        float v2; int i2;
        {
            float v = (lane == i0 || lane == i1) ? -INFINITY : logit; int ix = lane;
#pragma unroll
            for (int off = 32; off; off >>= 1) {
                const float vo = __shfl_xor(v, off);
                const int   io = __shfl_xor(ix, off);
                if (vo > v || (vo == v && io < ix)) { v = vo; ix = io; }
            }
            v2 = v; i2 = ix;
        }

        // near-tie guard: wave-parallel fp64 recompute of the 3 candidate
        // logits (lanes stride K by 64 -> coalesced; butterfly fp64 sum).
        // eps = 1e-3 vs main-path err sigma ~5e-6: ~200-sigma margin (proven).
        const float eps = 1e-3f;
        if ((v0 - v1) < eps || (v1 - v2) < eps) {
            const float* xr  = x + (size_t)g * D;
            const float* w0r = W + (size_t)i0 * D;
            const float* w1r = W + (size_t)i1 * D;
            const float* w2r = W + (size_t)i2 * D;
            double s0 = 0.0, s1 = 0.0, s2 = 0.0;
            for (int d = lane; d < D; d += 64) {
                const double xv = (double)xr[d];
                s0 += xv * (double)w0r[d];
                s1 += xv * (double)w1r[d];
                s2 += xv * (double)w2r[d];
            }
#pragma unroll
            for (int off = 32; off; off >>= 1) {
                s0 += __shfl_xor(s0, off);
                s1 += __shfl_xor(s1, off);
                s2 += __shfl_xor(s2, off);
            }
            double d0 = s0 + (double)noise[(size_t)g * EXPN + i0] * (double)nw[i0];
            double d1 = s1 + (double)noise[(size_t)g * EXPN + i1] * (double)nw[i1];
            double d2 = s2 + (double)noise[(size_t)g * EXPN + i2] * (double)nw[i2];
            // sort 3 (value desc, index asc on ties)
            #define CSWAP(va, ia, vb, ib)                                   \
                if ((vb > va) || (vb == va && ib < ia)) {                   \
                    double tv = va; va = vb; vb = tv;                       \
                    int ti = ia; ia = ib; ib = ti; }
            CSWAP(d0, i0, d1, i1)
            CSWAP(d1, i1, d2, i2)
            CSWAP(d0, i0, d1, i1)
            #undef CSWAP
            v0 = (float)d0; v1 = (float)d1;
        }

        const float e1  = expf(v1 - v0);
        const float inv = 1.0f / (1.0f + e1);

        float p = 0.f;
        if (lane == i0)      p = inv;
        else if (lane == i1) p = e1 * inv;
        probs[(size_t)g * EXPN + lane] = p;

        if (lane == 0) {
            idx_out[(size_t)g * 2 + 0] = (float)i0;
            idx_out[(size_t)g * 2 + 1] = (float)i1;
            val_out[(size_t)g * 2 + 0] = v0;
            val_out[(size_t)g * 2 + 1] = v1;
        }
    }
}

extern "C" void kernel_launch(void* const* d_in, const int* in_sizes, int n_in,
                              void* d_out, int out_size, void* d_ws, size_t ws_size,
                              hipStream_t stream) {
    const float* x     = (const float*)d_in[0];  // [B,S,D]
    const float* W     = (const float*)d_in[1];  // [E,D]
    const float* nw    = (const float*)d_in[2];  // [E]
    const float* noise = (const float*)d_in[3];  // [B,S,E]

    const int M = in_sizes[3] / EXPN;            // 16384 tokens
    const int D = in_sizes[0] / M;               // 2048
    const int wn = in_sizes[1];                  // E*D = 131072

    unsigned short* whp = (unsigned short*)d_ws;            // [E,D] bf16 hi
    unsigned short* wlp = whp + (size_t)wn;                 // [E,D] bf16 lo

    float* probs   = (float*)d_out;              // [M, E]
    float* idx_out = probs + (size_t)M * EXPN;   // [M, 2]
    float* val_out = idx_out + (size_t)M * 2;    // [M, 2]

    const int n4 = wn / 4;
    convert_w_kernel<<<(n4 + 255) / 256, 256, 0, stream>>>(W, whp, wlp, n4);

    const int grid = M / TM;                     // 512 blocks
    moe_gate_kernel<<<grid, 512, 0, stream>>>(x, W, whp, wlp, nw, noise,
                                              probs, idx_out, val_out, D);
}

// Round 8
// 215.119 us; speedup vs baseline: 1.0378x; 1.0378x over previous
//
#include <hip/hip_runtime.h>
#include <math.h>

// TopKMoEGate via split-bf16 MFMA:
//   x = xh + xl, W = wh + wl (bf16 hi/lo); logits = xh*wh + xh*wl + xl*wh
//   (fp32-accurate to ~5e-6; wave-parallel fp64 tie-guard on top-3 candidates).
// R15 = R14 resubmitted verbatim after an infra-level container failure (no
//     kernel signal). Audit found no hang/fault vector: uniform barriers,
//     LDS 128 KB < 160 KB segment, in-bounds DMA addressing, R13-proven
//     race discipline, VGPR estimate < the 128 cap of a 1024-thread block.
// R14: convoy-term reduction by geometry. Empirical model from R7/R9/R10/R13:
//     per-CU-chunk time ~ 3.1K cy fixed + staged_bytes/8.4 B/cy; inflated by
//     (a) 16x16 wave tiles reading each staged byte 2-4x from LDS and (b) W
//     re-staged per block (2 blocks/CU). Changes, all on the R13-proven
//     skeleton (DMA staging, raw s_barrier + lgkmcnt belt + fence, involution
//     swizzle, 3-term numerics, eps=1e-3 top-3 fp64 guard):
//     - 32x32 wave tiles (2x2 frags, 4 named accs): LDS reads halve.
//     - TM=64, 1024 thr, 16 waves = 4 K-slices x 2 tok-halves x 2 exp-halves;
//       grid 256 = 1 block/CU -> W staged ONCE per CU; K-partials summed in
//       LDS at the end (R8-proven combine).
//     - BK=128, NBUF=2 (128 KB LDS): 16 chunks -> half the barrier/fixed costs.
//       vmcnt(0)/iter is cheap (only chunk c in flight, issued a full iteration
//       earlier); overwrite distance = R13's proven 1-barrier + belt.

typedef __attribute__((ext_vector_type(8))) __bf16 bf16x8;
typedef __attribute__((ext_vector_type(8))) unsigned short u16x8;
typedef __attribute__((ext_vector_type(4))) float f32x4;
typedef __attribute__((ext_vector_type(4))) unsigned u32x4;

constexpr int EXPN = 64;    // experts
constexpr int TM   = 64;    // tokens per block
constexpr int BK   = 128;   // k per chunk
constexpr int WCH  = EXPN * BK * 2 * 2;   // 32768 B W chunk (hi+lo)
constexpr int XCH  = TM * BK * 4;         // 32768 B x chunk (fp32)
constexpr int BUF  = WCH + XCH;           // 65536 B per buffer
constexpr int NBUF = 2;                   // 128 KB -> 1 block/CU

__device__ __forceinline__ void split2(float f, unsigned short& h, unsigned short& l) {
    const unsigned b = __float_as_uint(f);
    h = (unsigned short)(b >> 16);                       // bf16 hi (truncate)
    const float fh = __uint_as_float(b & 0xffff0000u);
    l = (unsigned short)(__float_as_uint(f - fh) >> 16); // bf16 lo
}

__device__ __forceinline__ bf16x8 as_bf16(u16x8 v) {
    union { u16x8 u; bf16x8 b; } c; c.u = v; return c.b;
}
__device__ __forceinline__ bf16x8 as_bf16_u32(u32x4 v) {
    union { u32x4 u; bf16x8 b; } c; c.u = v; return c.b;
}

// perm-packed split2 of 8 fp32 -> bf16 hi/lo vectors (bit-identical to split2)
__device__ __forceinline__ void split_pack(float4 a, float4 c, bf16x8& hi, bf16x8& lo) {
    const unsigned u0=__float_as_uint(a.x), u1=__float_as_uint(a.y),
                   u2=__float_as_uint(a.z), u3=__float_as_uint(a.w),
                   u4=__float_as_uint(c.x), u5=__float_as_uint(c.y),
                   u6=__float_as_uint(c.z), u7=__float_as_uint(c.w);
    u32x4 hp, lp;
    hp[0] = __builtin_amdgcn_perm(u1, u0, 0x07060302u);
    hp[1] = __builtin_amdgcn_perm(u3, u2, 0x07060302u);
    hp[2] = __builtin_amdgcn_perm(u5, u4, 0x07060302u);
    hp[3] = __builtin_amdgcn_perm(u7, u6, 0x07060302u);
    const unsigned d0=__float_as_uint(a.x-__uint_as_float(u0&0xffff0000u));
    const unsigned d1=__float_as_uint(a.y-__uint_as_float(u1&0xffff0000u));
    const unsigned d2=__float_as_uint(a.z-__uint_as_float(u2&0xffff0000u));
    const unsigned d3=__float_as_uint(a.w-__uint_as_float(u3&0xffff0000u));
    const unsigned d4=__float_as_uint(c.x-__uint_as_float(u4&0xffff0000u));
    const unsigned d5=__float_as_uint(c.y-__uint_as_float(u5&0xffff0000u));
    const unsigned d6=__float_as_uint(c.z-__uint_as_float(u6&0xffff0000u));
    const unsigned d7=__float_as_uint(c.w-__uint_as_float(u7&0xffff0000u));
    lp[0] = __builtin_amdgcn_perm(d1, d0, 0x07060302u);
    lp[1] = __builtin_amdgcn_perm(d3, d2, 0x07060302u);
    lp[2] = __builtin_amdgcn_perm(d5, d4, 0x07060302u);
    lp[3] = __builtin_amdgcn_perm(d7, d6, 0x07060302u);
    hi = as_bf16_u32(hp); lo = as_bf16_u32(lp);
}

// async global -> LDS DMA, 16 B per lane; LDS dest = wave-uniform base + lane*16
__device__ __forceinline__ void gload16(const void* g, void* l) {
    typedef __attribute__((address_space(1))) void gv;
    typedef __attribute__((address_space(3))) void lv;
    __builtin_amdgcn_global_load_lds((gv*)g, (lv*)l, 16, 0, 0);
}

// ---- pre-kernel: W fp32 -> wh/wl bf16 planes (same split2 numerics) ----
__global__ __launch_bounds__(256)
void convert_w_kernel(const float* __restrict__ W,
                      unsigned short* __restrict__ whp,
                      unsigned short* __restrict__ wlp, int n4)
{
    const int i = blockIdx.x * 256 + threadIdx.x;   // float4 index
    if (i >= n4) return;
    const float4 v = *(const float4*)(W + (size_t)i * 4);
    const float f[4] = {v.x, v.y, v.z, v.w};
    unsigned short h[4], l[4];
#pragma unroll
    for (int j = 0; j < 4; ++j) split2(f[j], h[j], l[j]);
    *(ushort4*)(whp + (size_t)i * 4) = make_ushort4(h[0], h[1], h[2], h[3]);
    *(ushort4*)(wlp + (size_t)i * 4) = make_ushort4(l[0], l[1], l[2], l[3]);
}

#define MFMA16(a, b, c) __builtin_amdgcn_mfma_f32_16x16x32_bf16((a), (b), (c), 0, 0, 0)

__global__ __launch_bounds__(1024, 4)
void moe_gate_kernel(const float* __restrict__ x,      // [M, D]
                     const float* __restrict__ W,      // [E, D] (fp64 guard only)
                     const unsigned short* __restrict__ whp,  // [E, D] bf16 hi
                     const unsigned short* __restrict__ wlp,  // [E, D] bf16 lo
                     const float* __restrict__ nw,     // [E]
                     const float* __restrict__ noise,  // [M, E]
                     float* __restrict__ probs,        // [M, E]
                     float* __restrict__ idx_out,      // [M, 2] float-encoded
                     float* __restrict__ val_out,      // [M, 2]
                     int D)
{
    // buffer b at smem + b*BUF:
    //  W tile: 64 expert rows x 512 B (hi plane bytes [0,256) = 16 granules,
    //          lo plane [256,512) = granules 16..31)
    //  x tile at +WCH: 64 token rows x 512 B (128 fp32, 32 granules)
    // 16 B granules; phys slot p of row r holds logical granule
    //   (p & ~7) | ((p & 7) ^ (r & 7))    (involution; applied both sides)
    __shared__ __align__(16) char smem[NBUF * BUF];   // 128 KB

    const int tid  = threadIdx.x;
    const int lane = tid & 63;
    const int wv   = tid >> 6;          // 0..15
    const int kw   = wv >> 2;           // K slice 0..3 (32 k of the 128 chunk)
    const int th   = (wv >> 1) & 1;     // token half  (32 tokens)
    const int eh   = wv & 1;            // expert half (32 experts)
    const int m0   = blockIdx.x * TM;

    const int fr  = lane & 15;          // row within 16-row frag
    const int khi = lane >> 4;          // 0..3 (k sub-offset kq = khi*8)

    // ---- staging sources (pre-swizzled per-lane global pointers) ----
    const int sub  = lane >> 5;         // row within 1 KB inst (2 rows/inst)
    const int slot = lane & 31;         // phys granule slot within 512 B row
    // W: 32 insts/chunk, wave wv issues j0=2wv (rows 4wv+sub), j1 (rows +2)
    const int we0 = 4 * wv + sub, we1 = we0 + 2;
    const int wg0 = (slot & ~7) | ((slot & 7) ^ (we0 & 7));
    const int wg1 = (slot & ~7) | ((slot & 7) ^ (we1 & 7));
    const unsigned short* wsrc0 = ((wg0 < 16) ? whp : wlp)
                                + (size_t)we0 * D + (wg0 & 15) * 8;
    const unsigned short* wsrc1 = ((wg1 < 16) ? whp : wlp)
                                + (size_t)we1 * D + (wg1 & 15) * 8;
    // x: 32 insts/chunk, wave wv issues rows 4wv+sub and +2
    const int xt0 = 4 * wv + sub, xt1 = xt0 + 2;
    const int xg0 = (slot & ~7) | ((slot & 7) ^ (xt0 & 7));
    const int xg1 = (slot & ~7) | ((slot & 7) ^ (xt1 & 7));
    const float* xsrc0 = x + (size_t)(m0 + xt0) * D + xg0 * 4;
    const float* xsrc1 = x + (size_t)(m0 + xt1) * D + xg1 * 4;

#define STAGE(b, c) {                                                     \
        char* bb_ = smem + (b) * BUF;                                     \
        gload16(wsrc0 + (size_t)(c) * BK, bb_ + wv * 2048);               \
        gload16(wsrc1 + (size_t)(c) * BK, bb_ + wv * 2048 + 1024);        \
        gload16(xsrc0 + (size_t)(c) * BK, bb_ + WCH + wv * 2048);         \
        gload16(xsrc1 + (size_t)(c) * BK, bb_ + WCH + wv * 2048 + 1024);  \
    }

    f32x4 acc00 = {0.f,0.f,0.f,0.f};   // tok frag 0, exp frag 0
    f32x4 acc01 = {0.f,0.f,0.f,0.f};   // tok frag 0, exp frag 1
    f32x4 acc10 = {0.f,0.f,0.f,0.f};   // tok frag 1, exp frag 0
    f32x4 acc11 = {0.f,0.f,0.f,0.f};   // tok frag 1, exp frag 1

    // read-side constants
    const int t0 = th * 32 + fr, t1 = t0 + 16;       // t1&7 == t0&7
    const int e0 = eh * 32 + fr, e1 = e0 + 16;       // e1&7 == e0&7
    const int pa0 = kw * 8 + ((khi * 2)     ^ (t0 & 7));
    const int pa1 = kw * 8 + ((khi * 2 + 1) ^ (t0 & 7));
    const int gh  = kw * 4 + khi;                    // W hi granule 0..15
    const int pb  = (gh & ~7) | ((gh & 7) ^ (e0 & 7));

#define COMPUTE(b) {                                                            \
        const char* wbp_ = smem + (b) * BUF;                                    \
        const char* xbp_ = wbp_ + WCH;                                          \
        const float4 xa0_ = *(const float4*)(xbp_ + t0 * 512 + pa0 * 16);       \
        const float4 xc0_ = *(const float4*)(xbp_ + t0 * 512 + pa1 * 16);       \
        const float4 xa1_ = *(const float4*)(xbp_ + t1 * 512 + pa0 * 16);       \
        const float4 xc1_ = *(const float4*)(xbp_ + t1 * 512 + pa1 * 16);       \
        const u16x8 bh0_ = *(const u16x8*)(wbp_ + e0 * 512 + pb * 16);          \
        const u16x8 bl0_ = *(const u16x8*)(wbp_ + e0 * 512 + pb * 16 + 256);    \
        const u16x8 bh1_ = *(const u16x8*)(wbp_ + e1 * 512 + pb * 16);          \
        const u16x8 bl1_ = *(const u16x8*)(wbp_ + e1 * 512 + pb * 16 + 256);    \
        bf16x8 ah0_, al0_, ah1_, al1_;                                          \
        split_pack(xa0_, xc0_, ah0_, al0_);                                     \
        split_pack(xa1_, xc1_, ah1_, al1_);                                     \
        const bf16x8 h0_ = as_bf16(bh0_), l0_ = as_bf16(bl0_);                  \
        const bf16x8 h1_ = as_bf16(bh1_), l1_ = as_bf16(bl1_);                  \
        acc00 = MFMA16(ah0_, h0_, acc00);                                       \
        acc00 = MFMA16(ah0_, l0_, acc00);                                       \
        acc00 = MFMA16(al0_, h0_, acc00);                                       \
        acc01 = MFMA16(ah0_, h1_, acc01);                                       \
        acc01 = MFMA16(ah0_, l1_, acc01);                                       \
        acc01 = MFMA16(al0_, h1_, acc01);                                       \
        acc10 = MFMA16(ah1_, h0_, acc10);                                       \
        acc10 = MFMA16(ah1_, l0_, acc10);                                       \
        acc10 = MFMA16(al1_, h0_, acc10);                                       \
        acc11 = MFMA16(ah1_, h1_, acc11);                                       \
        acc11 = MFMA16(ah1_, l1_, acc11);                                       \
        acc11 = MFMA16(al1_, h1_, acc11);                                       \
    }

    const int nchunk = D / BK;          // 16
    STAGE(0, 0)

    for (int c = 0; c < nchunk; ++c) {
        // belt: my ds_reads from the previous iteration are COMPLETE before I
        // pass the barrier -> the STAGE issued after the barrier can never
        // overwrite a pending read.
        asm volatile("s_waitcnt lgkmcnt(0)" ::: "memory");
        // only chunk c in flight (issued a full iteration ago) -> cheap drain
        asm volatile("s_waitcnt vmcnt(0)" ::: "memory");
        __builtin_amdgcn_s_barrier();   // raw barrier
        asm volatile("" ::: "memory");  // fence: nothing hoists above
        if (c + 1 < nchunk) STAGE((c + 1) & 1, c + 1)
        COMPUTE(c & 1)
    }

#undef STAGE
#undef COMPUTE

    __syncthreads();   // all waves done with buffers; safe to alias partials

    // ---- K-partial store: C/D layout col = lane&15, row = (lane>>4)*4 + r ----
    float (*pl)[TM][EXPN + 1] = (float (*)[TM][EXPN + 1])smem;  // 4x64x65 fp32
    const int tr0 = th * 32 + khi * 4;
    const int ec0 = eh * 32 + fr;
#pragma unroll
    for (int r = 0; r < 4; ++r) {
        pl[kw][tr0 + r][ec0]           = acc00[r];
        pl[kw][tr0 + r][ec0 + 16]      = acc01[r];
        pl[kw][tr0 + 16 + r][ec0]      = acc10[r];
        pl[kw][tr0 + 16 + r][ec0 + 16] = acc11[r];
    }
    __syncthreads();

    // ---- epilogue: per-token noisy top-2 + sparse softmax (lane = expert) ----
    const float nwv = nw[lane];

#pragma unroll 1
    for (int t = 0; t < 4; ++t) {
        const int tl = wv * 4 + t;       // local token (16 waves x 4 = 64)
        const int g  = m0 + tl;          // global token
        const float lg = pl[0][tl][lane] + pl[1][tl][lane]
                       + pl[2][tl][lane] + pl[3][tl][lane];
        const float logit = fmaf(noise[(size_t)g * EXPN + lane], nwv, lg);

        float v0; int i0;
        {
            float v = logit; int ix = lane;
#pragma unroll
            for (int off = 32; off; off >>= 1) {
                const float vo = __shfl_xor(v, off);
                const int   io = __shfl_xor(ix, off);
                if (vo > v || (vo == v && io < ix)) { v = vo; ix = io; }
            }
            v0 = v; i0 = ix;
        }
        float v1; int i1;
        {
            float v = (lane == i0) ? -INFINITY : logit; int ix = lane;
#pragma unroll
            for (int off = 32; off; off >>= 1) {
                const float vo = __shfl_xor(v, off);
                const int   io = __shfl_xor(ix, off);
                if (vo > v || (vo == v && io < ix)) { v = vo; ix = io; }
            }
            v1 = v; i1 = ix;
        }
        float v2; int i2;
        {
            float v = (lane == i0 || lane == i1) ? -INFINITY : logit; int ix = lane;
#pragma unroll
            for (int off = 32; off; off >>= 1) {
                const float vo = __shfl_xor(v, off);
                const int   io = __shfl_xor(ix, off);
                if (vo > v || (vo == v && io < ix)) { v = vo; ix = io; }
            }
            v2 = v; i2 = ix;
        }

        // near-tie guard: wave-parallel fp64 recompute of the 3 candidate
        // logits (lanes stride K by 64 -> coalesced; butterfly fp64 sum).
        // eps = 1e-3 vs main-path err sigma ~5e-6: ~200-sigma margin (proven).
        const float eps = 1e-3f;
        if ((v0 - v1) < eps || (v1 - v2) < eps) {
            const float* xr  = x + (size_t)g * D;
            const float* w0r = W + (size_t)i0 * D;
            const float* w1r = W + (size_t)i1 * D;
            const float* w2r = W + (size_t)i2 * D;
            double s0 = 0.0, s1 = 0.0, s2 = 0.0;
            for (int d = lane; d < D; d += 64) {
                const double xv = (double)xr[d];
                s0 += xv * (double)w0r[d];
                s1 += xv * (double)w1r[d];
                s2 += xv * (double)w2r[d];
            }
#pragma unroll
            for (int off = 32; off; off >>= 1) {
                s0 += __shfl_xor(s0, off);
                s1 += __shfl_xor(s1, off);
                s2 += __shfl_xor(s2, off);
            }
            double d0 = s0 + (double)noise[(size_t)g * EXPN + i0] * (double)nw[i0];
            double d1 = s1 + (double)noise[(size_t)g * EXPN + i1] * (double)nw[i1];
            double d2 = s2 + (double)noise[(size_t)g * EXPN + i2] * (double)nw[i2];
            // sort 3 (value desc, index asc on ties)
            #define CSWAP(va, ia, vb, ib)                                   \
                if ((vb > va) || (vb == va && ib < ia)) {                   \
                    double tv = va; va = vb; vb = tv;                       \
                    int ti = ia; ia = ib; ib = ti; }
            CSWAP(d0, i0, d1, i1)
            CSWAP(d1, i1, d2, i2)
            CSWAP(d0, i0, d1, i1)
            #undef CSWAP
            v0 = (float)d0; v1 = (float)d1;
        }

        const float e1  = expf(v1 - v0);
        const float inv = 1.0f / (1.0f + e1);

        float p = 0.f;
        if (lane == i0)      p = inv;
        else if (lane == i1) p = e1 * inv;
        probs[(size_t)g * EXPN + lane] = p;

        if (lane == 0) {
            idx_out[(size_t)g * 2 + 0] = (float)i0;
            idx_out[(size_t)g * 2 + 1] = (float)i1;
            val_out[(size_t)g * 2 + 0] = v0;
            val_out[(size_t)g * 2 + 1] = v1;
        }
    }
}

extern "C" void kernel_launch(void* const* d_in, const int* in_sizes, int n_in,
                              void* d_out, int out_size, void* d_ws, size_t ws_size,
                              hipStream_t stream) {
    const float* x     = (const float*)d_in[0];  // [B,S,D]
    const float* W     = (const float*)d_in[1];  // [E,D]
    const float* nw    = (const float*)d_in[2];  // [E]
    const float* noise = (const float*)d_in[3];  // [B,S,E]

    const int M = in_sizes[3] / EXPN;            // 16384 tokens
    const int D = in_sizes[0] / M;               // 2048
    const int wn = in_sizes[1];                  // E*D = 131072

    unsigned short* whp = (unsigned short*)d_ws;            // [E,D] bf16 hi
    unsigned short* wlp = whp + (size_t)wn;                 // [E,D] bf16 lo

    float* probs   = (float*)d_out;              // [M, E]
    float* idx_out = probs + (size_t)M * EXPN;   // [M, 2]
    float* val_out = idx_out + (size_t)M * 2;    // [M, 2]

    const int n4 = wn / 4;
    convert_w_kernel<<<(n4 + 255) / 256, 256, 0, stream>>>(W, whp, wlp, n4);

    const int grid = M / TM;                     // 256 blocks (1 per CU)
    moe_gate_kernel<<<grid, 1024, 0, stream>>>(x, W, whp, wlp, nw, noise,
                                               probs, idx_out, val_out, D);
}